// Round 1
// baseline (297.916 us; speedup 1.0000x reference)
//
#include <hip/hip_runtime.h>

#define H 512
#define WID 1024
#define HW (H*WID)
#define B 4
#define K 8
#define NB 1024

// ws layout in 4-byte words
#define OFF_LOSS  0
#define OFF_STATS 16                      // B*K*5 = 160 floats: cnt,sx,sy,ss,ss2
#define OFF_FIN   (OFF_STATS + B*K*5)     // B*K*4 floats: cx,cy,sexp,cnt
#define OFF_CNTG  (OFF_FIN + B*K*4)       // B*K*NB u32
#define OFF_POSG  (OFF_CNTG + B*K*NB)     // B*K*NB u32
#define TOTAL_WORDS (OFF_POSG + B*K*NB)

// ---------------- Kernel 1: per-(b,k) mask statistics ----------------
__global__ __launch_bounds__(256) void k1_stats(const float* __restrict__ pred,
                                                const int* __restrict__ inst,
                                                float* __restrict__ ws) {
  const int b = blockIdx.y;
  const float* sig = pred + (size_t)(8*b + 5) * HW;   // channel 2, t=1
  const int*   ins = inst + (size_t)(2*b + 1) * HW;
  float cnt[K]={0}, sx[K]={0}, sy[K]={0}, ss[K]={0}, ss2[K]={0};
  const int tid = blockIdx.x * 256 + threadIdx.x;
  const int nth = gridDim.x * 256;
  for (int p = tid; p < HW; p += nth) {
    const int iv = ins[p];
    const float s = sig[p];
    const float xm = (float)(p & (WID-1)) * (2.0f/2047.0f);
    const float ym = (float)(p >> 10)     * (1.0f/1023.0f);
    #pragma unroll
    for (int k=0;k<K;k++){
      const float m = (iv == k+1) ? 1.0f : 0.0f;
      cnt[k]+=m; sx[k]+=m*xm; sy[k]+=m*ym; ss[k]+=m*s; ss2[k]+=m*s*s;
    }
  }
  #pragma unroll
  for (int k=0;k<K;k++){
    #pragma unroll
    for (int o=1;o<64;o<<=1){
      cnt[k]+=__shfl_xor(cnt[k],o,64);
      sx[k] +=__shfl_xor(sx[k], o,64);
      sy[k] +=__shfl_xor(sy[k], o,64);
      ss[k] +=__shfl_xor(ss[k], o,64);
      ss2[k]+=__shfl_xor(ss2[k],o,64);
    }
  }
  if ((threadIdx.x & 63) == 0) {
    #pragma unroll
    for (int k=0;k<K;k++){
      float* st = ws + OFF_STATS + (b*K + k)*5;
      atomicAdd(st+0, cnt[k]);
      atomicAdd(st+1, sx[k]);
      atomicAdd(st+2, sy[k]);
      atomicAdd(st+3, ss[k]);
      atomicAdd(st+4, ss2[k]);
    }
  }
}

// ---------------- Kernel 2: finalize stats + var loss ----------------
__global__ void k2_fin(float* __restrict__ ws) {
  const int t = threadIdx.x;
  if (t >= B*K) return;
  const float* st = ws + OFF_STATS + t*5;
  const float cnt = st[0], sx = st[1], sy = st[2], ss = st[3], ss2 = st[4];
  const float present = (cnt > 0.0f) ? 1.0f : 0.0f;
  const float safe = fmaxf(cnt, 1.0f);
  const float cx = sx/safe, cy = sy/safe, sm = ss/safe;
  // sum m*(sig - sm)^2 / safe  (N_SIGMA=1)
  const float var = (ss2 - 2.0f*sm*ss + sm*sm*cnt)/safe;
  const float sexp = expf(10.0f * sm);
  float* fin = ws + OFF_FIN + t*4;
  fin[0]=cx; fin[1]=cy; fin[2]=sexp; fin[3]=cnt;
  // W_VAR=10, /(B-1)=3
  atomicAdd(ws + OFF_LOSS, present * 10.0f * var * (1.0f/3.0f));
}

// ---------------- Kernel 3: main pass — histograms + seed/bg loss ----------------
__global__ __launch_bounds__(256) void k3_main(const float* __restrict__ pred,
                                               const int* __restrict__ inst,
                                               float* __restrict__ ws) {
  const int b = blockIdx.y;
  __shared__ unsigned int hist[K*NB];           // pos<<16 | cnt, 32 KiB
  for (int i = threadIdx.x; i < K*NB; i += 256) hist[i] = 0;
  float cx[K], cy[K], sexp[K];
  {
    const float* fin = ws + OFF_FIN + b*K*4;
    #pragma unroll
    for (int k=0;k<K;k++){ cx[k]=fin[4*k]; cy[k]=fin[4*k+1]; sexp[k]=fin[4*k+2]; }
  }
  __syncthreads();
  const float* p0 = pred + (size_t)(8*b+1)*HW;  // ch0 t=1
  const float* p1 = pred + (size_t)(8*b+3)*HW;  // ch1 t=1
  const float* p3 = pred + (size_t)(8*b+7)*HW;  // ch3 t=1
  const int*   ins = inst + (size_t)(2*b+1)*HW;
  float sAcc = 0.0f;                            // bg seed^2 + sum_k m*(seed-dist)^2
  const int start = blockIdx.x * (HW/64);       // gridDim.x = 64 -> 8192 px/block
  for (int q = threadIdx.x; q < HW/64; q += 256) {
    const int p = start + q;
    const int iv = ins[p];
    const float sex = tanhf(p0[p]) + (float)(p & (WID-1)) * (2.0f/2047.0f);
    const float sey = tanhf(p1[p]) + (float)(p >> 10)     * (1.0f/1023.0f);
    const float sd  = 1.0f / (1.0f + expf(-p3[p]));
    if (iv == 0) sAcc += sd*sd;
    #pragma unroll
    for (int k=0;k<K;k++){
      const float dx = sex - cx[k];
      const float dy = sey - cy[k];
      const float dist = expf(-sexp[k]*(dx*dx + dy*dy));  // in (0,1]
      const bool own = (iv == k+1);
      float e;
      if (own) { const float d = sd - dist; sAcc += d*d; e = 2.0f - 2.0f*dist; }
      else     { e = 2.0f*dist; }
      int bu = (int)(e * (NB*0.5f));
      if (bu > NB-1) bu = NB-1;
      atomicAdd(&hist[k*NB + bu], own ? 0x10001u : 1u);
    }
  }
  __syncthreads();
  unsigned int* wsu  = (unsigned int*)ws;
  unsigned int* cntG = wsu + OFF_CNTG + b*K*NB;
  unsigned int* posG = wsu + OFF_POSG + b*K*NB;
  for (int i = threadIdx.x; i < K*NB; i += 256) {
    const unsigned int v = hist[i];
    if (v) {
      atomicAdd(&cntG[i], v & 0xFFFFu);
      const unsigned int pz = v >> 16;
      if (pz) atomicAdd(&posG[i], pz);
    }
  }
  #pragma unroll
  for (int o=1;o<64;o<<=1) sAcc += __shfl_xor(sAcc, o, 64);
  __shared__ float wsum[4];
  if ((threadIdx.x & 63) == 0) wsum[threadIdx.x>>6] = sAcc;
  __syncthreads();
  if (threadIdx.x == 0) {
    const float tot = wsum[0]+wsum[1]+wsum[2]+wsum[3];
    // W_SEED=1, /npix, /(B-1)
    atomicAdd(ws + OFF_LOSS, tot * (1.0f/((float)HW * 3.0f)));
  }
}

// ---------------- Kernel 4: Lovász hinge from histograms ----------------
__global__ __launch_bounds__(256) void k4_lovasz(float* __restrict__ ws) {
  const int bk = blockIdx.x;                    // b*K + k
  const unsigned int* wsu  = (const unsigned int*)ws;
  const unsigned int* cntG = wsu + OFF_CNTG + bk*NB;
  const unsigned int* posG = wsu + OFF_POSG + bk*NB;
  const float cntF = ws[OFF_FIN + bk*4 + 3];
  if (cntF <= 0.0f) return;                     // present = 0
  const double Pd = (double)cntF;
  const int t = threadIdx.x;
  const int CHNK = NB/256;                      // 4 buckets per thread
  unsigned int mc[NB/256], mp[NB/256];
  int lc = 0, lp = 0;
  #pragma unroll
  for (int j=0;j<CHNK;j++){
    const int bu = NB-1 - (t*CHNK + j);         // descending error order
    mc[j] = cntG[bu]; mp[j] = posG[bu];
    lc += (int)mc[j]; lp += (int)mp[j];
  }
  __shared__ int sc[256], sp[256], ec[256], ep[256];
  sc[t]=lc; sp[t]=lp;
  __syncthreads();
  if (t==0){
    int a=0,c=0;
    for(int i=0;i<256;i++){ ec[i]=a; ep[i]=c; a+=sc[i]; c+=sp[i]; }
  }
  __syncthreads();
  int irun = ec[t], crun = ep[t];
  double acc = 0.0;
  #pragma unroll
  for (int j=0;j<CHNK;j++){
    const int bu = NB-1 - (t*CHNK + j);
    const int n = (int)mc[j];
    if (n) {
      const double jac0 = (irun==0) ? 0.0 : 1.0 - (Pd - crun)/(Pd + irun - crun);
      irun += n; crun += (int)mp[j];
      const double jac1 = 1.0 - (Pd - crun)/(Pd + irun - crun);
      acc += ((bu + 0.5) * (2.0/NB)) * (jac1 - jac0);
    }
  }
  __shared__ double racc[256];
  racc[t] = acc;
  __syncthreads();
  if (t==0){
    double tot=0.0;
    for (int i=0;i<256;i++) tot += racc[i];
    atomicAdd(ws + OFF_LOSS, (float)(tot * (1.0/3.0)));  // W_INST=1, /(B-1)
  }
}

// ---------------- Kernel 5: write output ----------------
__global__ void k5_out(const float* __restrict__ ws, float* __restrict__ out) {
  if (threadIdx.x == 0) out[0] = ws[OFF_LOSS];
}

extern "C" void kernel_launch(void* const* d_in, const int* in_sizes, int n_in,
                              void* d_out, int out_size, void* d_ws, size_t ws_size,
                              hipStream_t stream) {
  const float* pred = (const float*)d_in[0];
  const int*   inst = (const int*)d_in[1];
  float* ws  = (float*)d_ws;
  float* out = (float*)d_out;
  hipMemsetAsync(d_ws, 0, (size_t)TOTAL_WORDS*4, stream);
  k1_stats<<<dim3(64,B), 256, 0, stream>>>(pred, inst, ws);
  k2_fin  <<<1, 64, 0, stream>>>(ws);
  k3_main <<<dim3(64,B), 256, 0, stream>>>(pred, inst, ws);
  k4_lovasz<<<B*K, 256, 0, stream>>>(ws);
  k5_out  <<<1, 64, 0, stream>>>(ws, out);
}

// Round 2
// 241.798 us; speedup vs baseline: 1.2321x; 1.2321x over previous
//
#include <hip/hip_runtime.h>

#define H 512
#define WID 1024
#define HW (H*WID)
#define B 4
#define K 8
#define NB 1024

// ws layout in 4-byte words
#define OFF_LOSS  0
#define OFF_STATS 16                      // B*K*5 = 160 floats: cnt,sx,sy,ss,ss2
#define OFF_FIN   (OFF_STATS + B*K*5)     // B*K*4 floats: cx,cy,negsexp,cnt
#define OFF_CNTG  (OFF_FIN + B*K*4)       // B*K*NB u32
#define OFF_POSG  (OFF_CNTG + B*K*NB)     // B*K*NB u32
#define TOTAL_WORDS (OFF_POSG + B*K*NB)

static __device__ __forceinline__ float frcp(float x){
#if __has_builtin(__builtin_amdgcn_rcpf)
  return __builtin_amdgcn_rcpf(x);
#else
  return 1.0f / x;
#endif
}
// tanh(x) = 1 - 2/(e^{2x}+1); saturates correctly for |x| large (exp->inf/0)
static __device__ __forceinline__ float ftanh(float x){
  return 1.0f - 2.0f * frcp(__expf(2.0f*x) + 1.0f);
}
static __device__ __forceinline__ float fsigmoid(float x){
  return frcp(1.0f + __expf(-x));
}

// ---------------- Kernel 1: per-(b,k) mask statistics (wave-per-k) ----------------
// Block = 512 threads = 8 waves; wave w accumulates only k = w+1.
// 5 accumulators/thread -> no spill. Redundant inst reads served by L1/L2.
__global__ __launch_bounds__(512) void k1_stats(const float* __restrict__ pred,
                                                const int* __restrict__ inst,
                                                float* __restrict__ ws) {
  const int b = blockIdx.y;
  const int wv   = threadIdx.x >> 6;      // 0..7
  const int lane = threadIdx.x & 63;
  const int kk   = wv + 1;                // instance id this wave owns
  const float* sig = pred + (size_t)(8*b + 5) * HW;   // channel 2, t=1
  const int*   ins = inst + (size_t)(2*b + 1) * HW;
  const int CH   = HW / 64;               // gridDim.x = 64 -> 8192 px/block
  const int base = blockIdx.x * CH;
  float cnt=0.f, sx=0.f, sy=0.f, ss=0.f, ss2=0.f;
  for (int q = lane; q < CH; q += 64) {
    const int p = base + q;
    if (ins[p] == kk) {
      const float s  = sig[p];
      const float xm = (float)(p & (WID-1)) * (2.0f/2047.0f);
      const float ym = (float)(p >> 10)     * (1.0f/1023.0f);
      cnt += 1.0f; sx += xm; sy += ym; ss += s; ss2 += s*s;
    }
  }
  #pragma unroll
  for (int o=1;o<64;o<<=1){
    cnt+=__shfl_xor(cnt,o,64);
    sx +=__shfl_xor(sx, o,64);
    sy +=__shfl_xor(sy, o,64);
    ss +=__shfl_xor(ss, o,64);
    ss2+=__shfl_xor(ss2,o,64);
  }
  if (lane == 0) {
    float* st = ws + OFF_STATS + (b*K + wv)*5;
    atomicAdd(st+0, cnt);
    atomicAdd(st+1, sx);
    atomicAdd(st+2, sy);
    atomicAdd(st+3, ss);
    atomicAdd(st+4, ss2);
  }
}

// ---------------- Kernel 2: finalize stats + var loss ----------------
__global__ void k2_fin(float* __restrict__ ws) {
  const int t = threadIdx.x;
  if (t >= B*K) return;
  const float* st = ws + OFF_STATS + t*5;
  const float cnt = st[0], sx = st[1], sy = st[2], ss = st[3], ss2 = st[4];
  const float present = (cnt > 0.0f) ? 1.0f : 0.0f;
  const float safe = fmaxf(cnt, 1.0f);
  const float cx = sx/safe, cy = sy/safe, sm = ss/safe;
  const float var = (ss2 - 2.0f*sm*ss + sm*sm*cnt)/safe;   // N_SIGMA=1
  const float sexp = expf(10.0f * sm);
  float* fin = ws + OFF_FIN + t*4;
  fin[0]=cx; fin[1]=cy; fin[2]=-sexp; fin[3]=cnt;
  // W_VAR=10, /(B-1)=3
  atomicAdd(ws + OFF_LOSS, present * 10.0f * var * (1.0f/3.0f));
}

// ---------------- Kernel 3: main pass — histograms + seed/bg loss ----------------
__global__ __launch_bounds__(256) void k3_main(const float* __restrict__ pred,
                                               const int* __restrict__ inst,
                                               float* __restrict__ ws) {
  const int b = blockIdx.y;
  __shared__ unsigned int hist[K*NB];           // pos<<16 | cnt, 32 KiB
  __shared__ float4 finL[K];                    // {cx, cy, -sexp, cnt}
  for (int i = threadIdx.x; i < K*NB; i += 256) hist[i] = 0;
  if (threadIdx.x < K) {
    const float* fin = ws + OFF_FIN + (b*K + threadIdx.x)*4;
    finL[threadIdx.x] = make_float4(fin[0], fin[1], fin[2], fin[3]);
  }
  __syncthreads();
  const float* p0 = pred + (size_t)(8*b+1)*HW;  // ch0 t=1
  const float* p1 = pred + (size_t)(8*b+3)*HW;  // ch1 t=1
  const float* p3 = pred + (size_t)(8*b+7)*HW;  // ch3 t=1
  const int*   ins = inst + (size_t)(2*b+1)*HW;
  const int lane = threadIdx.x & 63;
  float sAcc = 0.0f;                            // bg seed^2 + sum_k m*(seed-dist)^2
  const int start = blockIdx.x * (HW/64);       // gridDim.x = 64 -> 8192 px/block
  for (int q = threadIdx.x; q < HW/64; q += 256) {
    const int p = start + q;
    const int iv = ins[p];
    const float sex = ftanh(p0[p]) + (float)(p & (WID-1)) * (2.0f/2047.0f);
    const float sey = ftanh(p1[p]) + (float)(p >> 10)     * (1.0f/1023.0f);
    const float sd  = fsigmoid(p3[p]);
    if (iv == 0) sAcc += sd*sd;
    // lane-rotated k order: at any instant the wave's 64 lanes hit 8 different
    // k-histograms -> same-address atomic degree <= 8 instead of up to 64.
    #pragma unroll
    for (int j=0;j<K;j++){
      const int k = (j + lane) & (K-1);
      const float4 f = finL[k];                 // ds_read_b128, broadcast per k-group
      const float dx = sex - f.x;
      const float dy = sey - f.y;
      const float dist = __expf(f.z*(dx*dx + dy*dy));  // in (0,1]
      const bool own = (iv == k+1);
      float e;
      if (own) { const float d = sd - dist; sAcc += d*d; e = 2.0f - 2.0f*dist; }
      else     { e = 2.0f*dist; }
      int bu = (int)(e * (NB*0.5f));
      if (bu > NB-1) bu = NB-1;
      atomicAdd(&hist[k*NB + bu], own ? 0x10001u : 1u);
    }
  }
  __syncthreads();
  unsigned int* wsu  = (unsigned int*)ws;
  unsigned int* cntG = wsu + OFF_CNTG + b*K*NB;
  unsigned int* posG = wsu + OFF_POSG + b*K*NB;
  for (int i = threadIdx.x; i < K*NB; i += 256) {
    const unsigned int v = hist[i];
    if (v) {
      atomicAdd(&cntG[i], v & 0xFFFFu);
      const unsigned int pz = v >> 16;
      if (pz) atomicAdd(&posG[i], pz);
    }
  }
  #pragma unroll
  for (int o=1;o<64;o<<=1) sAcc += __shfl_xor(sAcc, o, 64);
  __shared__ float wsum[4];
  if ((threadIdx.x & 63) == 0) wsum[threadIdx.x>>6] = sAcc;
  __syncthreads();
  if (threadIdx.x == 0) {
    const float tot = wsum[0]+wsum[1]+wsum[2]+wsum[3];
    // W_SEED=1, /npix, /(B-1)
    atomicAdd(ws + OFF_LOSS, tot * (1.0f/((float)HW * 3.0f)));
  }
}

// ---------------- Kernel 4: Lovász hinge from histograms ----------------
__global__ __launch_bounds__(256) void k4_lovasz(float* __restrict__ ws) {
  const int bk = blockIdx.x;                    // b*K + k
  const unsigned int* wsu  = (const unsigned int*)ws;
  const unsigned int* cntG = wsu + OFF_CNTG + bk*NB;
  const unsigned int* posG = wsu + OFF_POSG + bk*NB;
  const float cntF = ws[OFF_FIN + bk*4 + 3];
  if (cntF <= 0.0f) return;                     // present = 0
  const double Pd = (double)cntF;
  const int t = threadIdx.x;
  const int CHNK = NB/256;                      // 4 buckets per thread
  unsigned int mc[NB/256], mp[NB/256];
  int lc = 0, lp = 0;
  #pragma unroll
  for (int j=0;j<CHNK;j++){
    const int bu = NB-1 - (t*CHNK + j);         // descending error order
    mc[j] = cntG[bu]; mp[j] = posG[bu];
    lc += (int)mc[j]; lp += (int)mp[j];
  }
  __shared__ int sc[256], sp[256], ec[256], ep[256];
  sc[t]=lc; sp[t]=lp;
  __syncthreads();
  if (t==0){
    int a=0,c=0;
    for(int i=0;i<256;i++){ ec[i]=a; ep[i]=c; a+=sc[i]; c+=sp[i]; }
  }
  __syncthreads();
  int irun = ec[t], crun = ep[t];
  double acc = 0.0;
  #pragma unroll
  for (int j=0;j<CHNK;j++){
    const int bu = NB-1 - (t*CHNK + j);
    const int n = (int)mc[j];
    if (n) {
      const double jac0 = (irun==0) ? 0.0 : 1.0 - (Pd - crun)/(Pd + irun - crun);
      irun += n; crun += (int)mp[j];
      const double jac1 = 1.0 - (Pd - crun)/(Pd + irun - crun);
      acc += ((bu + 0.5) * (2.0/NB)) * (jac1 - jac0);
    }
  }
  __shared__ double racc[256];
  racc[t] = acc;
  __syncthreads();
  if (t==0){
    double tot=0.0;
    for (int i=0;i<256;i++) tot += racc[i];
    atomicAdd(ws + OFF_LOSS, (float)(tot * (1.0/3.0)));  // W_INST=1, /(B-1)
  }
}

// ---------------- Kernel 5: write output ----------------
__global__ void k5_out(const float* __restrict__ ws, float* __restrict__ out) {
  if (threadIdx.x == 0) out[0] = ws[OFF_LOSS];
}

extern "C" void kernel_launch(void* const* d_in, const int* in_sizes, int n_in,
                              void* d_out, int out_size, void* d_ws, size_t ws_size,
                              hipStream_t stream) {
  const float* pred = (const float*)d_in[0];
  const int*   inst = (const int*)d_in[1];
  float* ws  = (float*)d_ws;
  float* out = (float*)d_out;
  hipMemsetAsync(d_ws, 0, (size_t)TOTAL_WORDS*4, stream);
  k1_stats<<<dim3(64,B), 512, 0, stream>>>(pred, inst, ws);
  k2_fin  <<<1, 64, 0, stream>>>(ws);
  k3_main <<<dim3(64,B), 256, 0, stream>>>(pred, inst, ws);
  k4_lovasz<<<B*K, 256, 0, stream>>>(ws);
  k5_out  <<<1, 64, 0, stream>>>(ws, out);
}